// Round 3
// baseline (255.720 us; speedup 1.0000x reference)
//
#include <hip/hip_runtime.h>

// RBDispatcher R5: fused double-gather + concat, with register-level source-row
// dedup for the top_k-duplicated s1 section.
//   out[0 .. n_s2)         = x[ idx_s1[ idx_s2[r] ] / top_k ]   (random gather)
//   out[n_s2 .. n_s2+n_s1) = x[ idx_s1[r - n_s2] / top_k ]      (monotone copy)
//
// R5 changes vs R4 (2-deep pipelined rows, 255.2us):
//  - DEDUP: idx_s1 is sorted and top_k=2, so ~57% of consecutive s1 rows map
//    to the SAME x source row (Poisson(2) bins). Each wave handles 4
//    consecutive rows; if s[k]==s[k-1] we skip the 8KB re-load and store the
//    register buffer again. Saves ~43% of s1 read traffic (~57MB of 402MB
//    total) -- the first version to reduce BYTES rather than restructure.
//  - Dropped the A/B pipeline (R4 proved it neutral); simple load-once/
//    store-n loop, wave-uniform branch (s[] is scalar, no divergence).

typedef float v4f __attribute__((ext_vector_type(4)));

__device__ __forceinline__ void load_row(const float* __restrict__ src,
                                         int lane, v4f t[8]) {
  const v4f* __restrict__ sp = (const v4f*)src;
#pragma unroll
  for (int i = 0; i < 8; ++i) t[i] = sp[lane + 64 * i];   // cached: keep x in L2/LLC
}

__device__ __forceinline__ void store_row_nt(float* __restrict__ dst,
                                             int lane, const v4f t[8]) {
  v4f* __restrict__ dp = (v4f*)dst;
#pragma unroll
  for (int i = 0; i < 8; ++i)
    __builtin_nontemporal_store(t[i], dp + lane + 64 * i); // streaming writes
}

// Fast path, d==2048. Wave g handles rows [4g, 4g+4).
__global__ __launch_bounds__(256, 4) void rb_dispatch_r5(
    const float* __restrict__ x,
    const int* __restrict__ idx_s1,
    const int* __restrict__ idx_s2,
    const int* __restrict__ top_k_ptr,
    float* __restrict__ out,
    int n_s2, int n_rows) {
  const int wave = threadIdx.x >> 6;
  const int lane = threadIdx.x & 63;
  const int r0 = (blockIdx.x * 4 + wave) * 4;
  if (r0 >= n_rows) return;
  const int tk = *top_k_ptr;

  int s[4];
#pragma unroll
  for (int k = 0; k < 4; ++k) {
    const int r = r0 + k;                       // wave-uniform -> scalarized
    s[k] = (r < n_s2) ? (idx_s1[idx_s2[r]] / tk)
                      : (idx_s1[r - n_s2] / tk);
  }

  float* __restrict__ dst = out + (size_t)r0 * 2048;

  v4f t[8];
  int cur = -1;
#pragma unroll
  for (int k = 0; k < 4; ++k) {
    if (s[k] != cur) {                          // wave-uniform branch
      load_row(x + (size_t)s[k] * 2048, lane, t);
      cur = s[k];
    }
    store_row_nt(dst + (size_t)k * 2048, lane, t);
  }
}

// Generic fallback (any d / row count): R2 fused wave-per-row kernel.
__global__ __launch_bounds__(256) void rb_dispatch_generic(
    const float* __restrict__ x,
    const int* __restrict__ idx_s1,
    const int* __restrict__ idx_s2,
    const int* __restrict__ top_k_ptr,
    float* __restrict__ out,
    int n_s2, int n_rows, int nvec) {
  const int wave = threadIdx.x >> 6;
  const int lane = threadIdx.x & 63;
  const int row = blockIdx.x * 4 + wave;
  if (row >= n_rows) return;
  const int top_k = *top_k_ptr;
  int src;
  if (row < n_s2) src = idx_s1[idx_s2[row]] / top_k;
  else            src = idx_s1[row - n_s2] / top_k;
  const int d = nvec * 4;
  const v4f* __restrict__ sp = (const v4f*)(x + (size_t)src * (size_t)d);
  v4f* __restrict__ dp = (v4f*)(out + (size_t)row * (size_t)d);
#pragma unroll 4
  for (int i = lane; i < nvec; i += 64) {
    v4f v = sp[i];
    __builtin_nontemporal_store(v, dp + i);
  }
}

extern "C" void kernel_launch(void* const* d_in, const int* in_sizes, int n_in,
                              void* d_out, int out_size, void* d_ws, size_t ws_size,
                              hipStream_t stream) {
  const float* x      = (const float*)d_in[0];
  const int*   idx_s1 = (const int*)d_in[1];
  const int*   idx_s2 = (const int*)d_in[2];
  // d_in[3] = n_tokens (unused), d_in[4] = top_k (device scalar)
  const int*   top_k  = (const int*)d_in[4];
  float*       out    = (float*)d_out;

  const int n_s1   = in_sizes[1];       // 16384
  const int n_s2   = in_sizes[2];       // 8192
  const int n_rows = n_s1 + n_s2;       // 24576
  const int d      = out_size / n_rows; // 2048

  if (d == 2048 && (n_rows & 3) == 0 && (n_s2 & 3) == 0) {
    // 16 rows per block; 24576/16 = 1536 blocks, no tail.
    const int grid = n_rows / 16;
    rb_dispatch_r5<<<grid, 256, 0, stream>>>(
        x, idx_s1, idx_s2, top_k, out, n_s2, n_rows);
  } else {
    const int nvec = d / 4;
    const int grid = (n_rows + 3) / 4;
    rb_dispatch_generic<<<grid, 256, 0, stream>>>(
        x, idx_s1, idx_s2, top_k, out, n_s2, n_rows, nvec);
  }
}